// Round 1
// baseline (1161.819 us; speedup 1.0000x reference)
//
#include <hip/hip_runtime.h>

// ---------------- common types / helpers ----------------
typedef unsigned short u16;
typedef short s8v __attribute__((ext_vector_type(8)));
typedef float f4v __attribute__((ext_vector_type(4)));

__device__ __forceinline__ float bf2f(u16 u){ return __uint_as_float(((unsigned)u)<<16); }
__device__ __forceinline__ u16 f2bf(float f){
  unsigned u = __float_as_uint(f);
  unsigned r = u + 0x7fffu + ((u>>16)&1u);   // RNE
  return (u16)(r>>16);
}
__device__ __forceinline__ void gload16(const void* g, void* l){
  __builtin_amdgcn_global_load_lds((const __attribute__((address_space(1))) void*)g,
                                   (__attribute__((address_space(3))) void*)l, 16, 0, 0);
}

// ---------------- batched transpose + f32->bf16 convert ----------------
struct TJobs {
  const float* src[18];
  u16* dst[18];
  int R[18];
  int C[18];
  int start[19];
};

__global__ __launch_bounds__(256) void transpose_pack(TJobs jb){
  __shared__ float tile[32][33];
  int bid = blockIdx.x;
  int j = 0;
  while (bid >= jb.start[j+1]) j++;
  int t = bid - jb.start[j];
  int C = jb.C[j], R = jb.R[j];
  int ctiles = C >> 5;
  int ty = t / ctiles, tx = t - ty*ctiles;
  const float* src = jb.src[j];
  u16* dst = jb.dst[j];
  int tid = threadIdx.x;
  #pragma unroll
  for (int i=0;i<4;i++){
    int e = tid*4 + i;
    int lr = e >> 5, lc = e & 31;
    tile[lr][lc] = src[(long)(ty*32+lr)*C + tx*32+lc];
  }
  __syncthreads();
  #pragma unroll
  for (int i=0;i<4;i++){
    int e = tid*4 + i;
    int lc = e >> 5, lr = e & 31;
    dst[(long)(tx*32+lc)*R + ty*32+lr] = f2bf(tile[lr][lc]);
  }
}

__global__ __launch_bounds__(256) void pack_bias(const float* __restrict__ bq, const float* __restrict__ bk,
                                                 const float* __restrict__ bv, float* __restrict__ outp){
  int t = blockIdx.x*256 + threadIdx.x;
  if (t >= 3*3072) return;
  int l = t / 3072, c = t - l*3072;
  float v = (c < 1024) ? bq[l*1024+c] : (c < 2048) ? bk[l*1024+c-1024] : bv[l*1024+c-2048];
  outp[t] = v;
}

// ---------------- RoPE table + apply ----------------
__global__ __launch_bounds__(256) void rope_table(const int* __restrict__ pos, float* __restrict__ cosT,
                                                  float* __restrict__ sinT){
  int t = blockIdx.x*256 + threadIdx.x;     // 4096*32
  int j = t & 31, s = t >> 5;
  float f = expf(-(float)j * 0.28782313662425572f);   // ln(10000)/32
  float ang = (float)pos[s] * f;
  cosT[t] = cosf(ang);
  sinT[t] = sinf(ang);
}

__global__ __launch_bounds__(256) void rope_apply(const u16* __restrict__ qkv, const float* __restrict__ cosT,
                                                  const float* __restrict__ sinT, u16* __restrict__ qr,
                                                  u16* __restrict__ kr, u16* __restrict__ vr){
  int t = blockIdx.x*256 + threadIdx.x;     // 4096*16*32
  int j = t & 31, h = (t>>5) & 15, s = t >> 9;
  float c = cosT[(s<<5)+j], sn = sinT[(s<<5)+j];
  long base = (long)s*3072 + h*64 + j;
  long ob   = (long)s*1024 + h*64 + j;
  float q0 = bf2f(qkv[base]),      q1 = bf2f(qkv[base+32]);
  float k0 = bf2f(qkv[base+1024]), k1 = bf2f(qkv[base+1056]);
  qr[ob] = f2bf(q0*c - q1*sn);  qr[ob+32] = f2bf(q1*c + q0*sn);
  kr[ob] = f2bf(k0*c - k1*sn);  kr[ob+32] = f2bf(k1*c + k0*sn);
  vr[ob] = qkv[base+2048];      vr[ob+32] = qkv[base+2080];
}

// ---------------- LayerNorm ----------------
__device__ __forceinline__ float block_sum(float v, float* red, int tid){
  #pragma unroll
  for (int m=1;m<64;m<<=1) v += __shfl_xor(v, m);
  int w = tid >> 6;
  if ((tid & 63) == 0) red[w] = v;
  __syncthreads();
  float r = red[0]+red[1]+red[2]+red[3];
  __syncthreads();
  return r;
}

template<int OUTF32>
__global__ __launch_bounds__(256) void ln_kernel(const float* __restrict__ x, const float* __restrict__ g,
                                                 const float* __restrict__ b, float* __restrict__ outF,
                                                 u16* __restrict__ outH){
  __shared__ float red[4];
  long row = blockIdx.x;
  int tid = threadIdx.x;
  const float4 xv = *reinterpret_cast<const float4*>(x + row*1024 + tid*4);
  float s = xv.x + xv.y + xv.z + xv.w;
  float mean = block_sum(s, red, tid) * (1.0f/1024.0f);
  float d0 = xv.x-mean, d1 = xv.y-mean, d2 = xv.z-mean, d3 = xv.w-mean;
  float ss = d0*d0 + d1*d1 + d2*d2 + d3*d3;
  float var = block_sum(ss, red, tid) * (1.0f/1024.0f);
  float rstd = rsqrtf(var + 1e-5f);
  int c = tid*4;
  const float4 gv = *reinterpret_cast<const float4*>(g + c);
  const float4 bv = *reinterpret_cast<const float4*>(b + c);
  float y0 = d0*rstd*gv.x + bv.x, y1 = d1*rstd*gv.y + bv.y;
  float y2 = d2*rstd*gv.z + bv.z, y3 = d3*rstd*gv.w + bv.w;
  if (OUTF32){
    float4 o; o.x=y0; o.y=y1; o.z=y2; o.w=y3;
    *reinterpret_cast<float4*>(outF + row*1024 + c) = o;
  } else {
    outH[row*1024 + c+0] = f2bf(y0);
    outH[row*1024 + c+1] = f2bf(y1);
    outH[row*1024 + c+2] = f2bf(y2);
    outH[row*1024 + c+3] = f2bf(y3);
  }
}

// ---------------- GEMM: C = A[M,K] * BT[N,K]^T (+bias, epilogue) ----------------
// EPI 0: outH = bf16(acc+bias)
// EPI 1: outF = resid + acc + bias   (f32)
// EPI 2: outH = bf16(gelu(acc+bias)) (exact gelu)
template<int EPI>
__global__ __launch_bounds__(256) void gemm_bt(const u16* __restrict__ A, const u16* __restrict__ BT,
                                               const float* __restrict__ bias, const float* __restrict__ resid,
                                               float* __restrict__ outF, u16* __restrict__ outH,
                                               int M, int N, int K){
  __shared__ u16 As[4096];   // [128][32]
  __shared__ u16 Bs[4096];   // [128][32] (rows = output cols)
  const int tid = threadIdx.x;
  const int bn = blockIdx.x, bm = blockIdx.y;
  const int w = tid >> 6, lane = tid & 63;
  const int wr = w >> 1, wc = w & 1;
  const int l15 = lane & 15, k8 = (lane >> 4) * 8;

  f4v acc[4][4];
  #pragma unroll
  for (int i=0;i<4;i++)
    #pragma unroll
    for (int j=0;j<4;j++)
      acc[i][j] = (f4v){0.f,0.f,0.f,0.f};

  const int fe = tid * 8;                 // element offset of this thread's 16B chunk
  const int r0 = fe >> 5, c0 = fe & 31;   // rows 0..63
  const u16* ga0 = A  + ((long)(bm*128 + r0))*K + c0;
  const u16* gb0 = BT + ((long)(bn*128 + r0))*K + c0;
  const u16* ga1 = ga0 + (long)64*K;      // rows 64..127
  const u16* gb1 = gb0 + (long)64*K;

  for (int k0 = 0; k0 < K; k0 += 32){
    __syncthreads();
    gload16(ga0 + k0, &As[fe]);
    gload16(ga1 + k0, &As[fe + 2048]);
    gload16(gb0 + k0, &Bs[fe]);
    gload16(gb1 + k0, &Bs[fe + 2048]);
    __syncthreads();
    s8v af[4], bfr[4];
    #pragma unroll
    for (int i=0;i<4;i++){
      af[i]  = *(const s8v*)&As[(wr*64 + i*16 + l15)*32 + k8];
      bfr[i] = *(const s8v*)&Bs[(wc*64 + i*16 + l15)*32 + k8];
    }
    #pragma unroll
    for (int mi=0;mi<4;mi++)
      #pragma unroll
      for (int nf=0;nf<4;nf++)
        acc[mi][nf] = __builtin_amdgcn_mfma_f32_16x16x32_bf16(af[mi], bfr[nf], acc[mi][nf], 0, 0, 0);
  }

  const int r4 = (lane >> 4) * 4;
  #pragma unroll
  for (int mi=0;mi<4;mi++){
    int row = bm*128 + wr*64 + mi*16 + r4;
    #pragma unroll
    for (int nf=0;nf<4;nf++){
      int col = bn*128 + wc*64 + nf*16 + l15;
      float bcol = bias[col];
      #pragma unroll
      for (int r=0;r<4;r++){
        float v = acc[mi][nf][r] + bcol;
        long idx = (long)(row + r)*N + col;
        if (EPI == 0){
          outH[idx] = f2bf(v);
        } else if (EPI == 1){
          outF[idx] = resid[idx] + v;
        } else {
          float gl = 0.5f*v*(1.0f + erff(v*0.70710678118654752f));
          outH[idx] = f2bf(gl);
        }
      }
    }
  }
}

// ---------------- sliding-window attention (flash per 32-query wave tile) ----------------
// qr/kr/vr: [4096][16*64] bf16 ; ao: [4096][1024] bf16
__global__ __launch_bounds__(256) void attn_kernel(const u16* __restrict__ qr, const u16* __restrict__ kr,
                                                   const u16* __restrict__ vr, u16* __restrict__ ao){
  __shared__ u16 Pl[4][1280];   // per-wave [32][40]
  __shared__ u16 Vl[4][2304];   // per-wave [32][72]
  const int tid = threadIdx.x, w = tid >> 6, lane = tid & 63;
  const int task = blockIdx.x*4 + w;        // 2048 tasks
  const int head = task >> 7;
  const int q0 = (task & 127) * 32;
  const int l15 = lane & 15, lg = lane >> 4, k8 = lg * 8;

  s8v aq[2][2];
  #pragma unroll
  for (int mi=0;mi<2;mi++)
    #pragma unroll
    for (int kf=0;kf<2;kf++)
      aq[mi][kf] = *(const s8v*)&qr[(long)(q0 + mi*16 + l15)*1024 + head*64 + kf*32 + k8];

  f4v o[2][4];
  #pragma unroll
  for (int i=0;i<2;i++)
    #pragma unroll
    for (int j=0;j<4;j++)
      o[i][j] = (f4v){0.f,0.f,0.f,0.f};
  float mrun[2][4], lrun[2][4];
  #pragma unroll
  for (int i=0;i<2;i++)
    #pragma unroll
    for (int r=0;r<4;r++){ mrun[i][r] = -1e30f; lrun[i][r] = 0.f; }

  const int ktlo = (q0 >= 512) ? ((q0 - 511) >> 5) : 0;
  const int kthi = (q0 + 31) >> 5;

  for (int kt = ktlo; kt <= kthi; ++kt){
    const int k0 = kt * 32;
    // stage V tile [32][64] -> Vl[32][72]
    #pragma unroll
    for (int t=0;t<4;t++){
      int e = t*64 + lane;
      int r = e >> 3, c8 = (e & 7) * 8;
      *(s8v*)&Vl[w][r*72 + c8] = *(const s8v*)&vr[(long)(k0 + r)*1024 + head*64 + c8];
    }
    // QK^T
    s8v bk[2][2];
    #pragma unroll
    for (int nf=0;nf<2;nf++)
      #pragma unroll
      for (int kf=0;kf<2;kf++)
        bk[nf][kf] = *(const s8v*)&kr[(long)(k0 + nf*16 + l15)*1024 + head*64 + kf*32 + k8];
    f4v s[2][2];
    #pragma unroll
    for (int mi=0;mi<2;mi++)
      #pragma unroll
      for (int nf=0;nf<2;nf++){
        f4v z = (f4v){0.f,0.f,0.f,0.f};
        z = __builtin_amdgcn_mfma_f32_16x16x32_bf16(aq[mi][0], bk[nf][0], z, 0,0,0);
        z = __builtin_amdgcn_mfma_f32_16x16x32_bf16(aq[mi][1], bk[nf][1], z, 0,0,0);
        s[mi][nf] = z;
      }
    // online softmax (rows live in (lg, r); cols in l15 x nf)
    float alpha[2][4];
    #pragma unroll
    for (int mi=0;mi<2;mi++){
      #pragma unroll
      for (int r=0;r<4;r++){
        int q = q0 + mi*16 + lg*4 + r;
        int kk0 = k0 + l15, kk1 = k0 + 16 + l15;
        bool ok0 = (kk0 <= q) && (q - kk0 < 512);
        bool ok1 = (kk1 <= q) && (q - kk1 < 512);
        float sv0 = ok0 ? s[mi][0][r]*0.125f : -1e30f;
        float sv1 = ok1 ? s[mi][1][r]*0.125f : -1e30f;
        float tm = fmaxf(sv0, sv1);
        tm = fmaxf(tm, __shfl_xor(tm, 1));
        tm = fmaxf(tm, __shfl_xor(tm, 2));
        tm = fmaxf(tm, __shfl_xor(tm, 4));
        tm = fmaxf(tm, __shfl_xor(tm, 8));
        float mnew = fmaxf(mrun[mi][r], tm);
        float al = __expf(mrun[mi][r] - mnew);
        float p0 = ok0 ? __expf(sv0 - mnew) : 0.f;
        float p1 = ok1 ? __expf(sv1 - mnew) : 0.f;
        float rs = p0 + p1;
        rs += __shfl_xor(rs, 1);
        rs += __shfl_xor(rs, 2);
        rs += __shfl_xor(rs, 4);
        rs += __shfl_xor(rs, 8);
        mrun[mi][r] = mnew;
        lrun[mi][r] = lrun[mi][r]*al + rs;
        alpha[mi][r] = al;
        s[mi][0][r] = p0;
        s[mi][1][r] = p1;
      }
      #pragma unroll
      for (int df=0;df<4;df++)
        #pragma unroll
        for (int r=0;r<4;r++)
          o[mi][df][r] *= alpha[mi][r];
    }
    // P bounce: C-layout -> A-layout via LDS
    #pragma unroll
    for (int mi=0;mi<2;mi++)
      #pragma unroll
      for (int nf=0;nf<2;nf++)
        #pragma unroll
        for (int r=0;r<4;r++)
          Pl[w][(mi*16 + lg*4 + r)*40 + nf*16 + l15] = f2bf(s[mi][nf][r]);
    s8v ap[2];
    #pragma unroll
    for (int mi=0;mi<2;mi++)
      ap[mi] = *(const s8v*)&Pl[w][(mi*16 + l15)*40 + k8];
    s8v bv[4];
    #pragma unroll
    for (int df=0;df<4;df++){
      #pragma unroll
      for (int i=0;i<8;i++)
        bv[df][i] = (short)Vl[w][(k8 + i)*72 + df*16 + l15];
    }
    #pragma unroll
    for (int mi=0;mi<2;mi++)
      #pragma unroll
      for (int df=0;df<4;df++)
        o[mi][df] = __builtin_amdgcn_mfma_f32_16x16x32_bf16(ap[mi], bv[df], o[mi][df], 0,0,0);
  }
  // epilogue
  #pragma unroll
  for (int mi=0;mi<2;mi++)
    #pragma unroll
    for (int df=0;df<4;df++)
      #pragma unroll
      for (int r=0;r<4;r++){
        long row = q0 + mi*16 + lg*4 + r;
        int col = head*64 + df*16 + l15;
        ao[row*1024 + col] = f2bf(o[mi][df][r] / lrun[mi][r]);
      }
}

// ---------------- host ----------------
extern "C" void kernel_launch(void* const* d_in, const int* in_sizes, int n_in,
                              void* d_out, int out_size, void* d_ws, size_t ws_size,
                              hipStream_t stream){
  const float* hidden = (const float*)d_in[0];
  const int*   pos    = (const int*)d_in[1];
  const float* ln1_g  = (const float*)d_in[2];
  const float* ln1_b  = (const float*)d_in[3];
  const float* wq     = (const float*)d_in[4];
  const float* bq     = (const float*)d_in[5];
  const float* wk     = (const float*)d_in[6];
  const float* bk     = (const float*)d_in[7];
  const float* wv     = (const float*)d_in[8];
  const float* bv     = (const float*)d_in[9];
  const float* wo     = (const float*)d_in[10];
  const float* bo     = (const float*)d_in[11];
  const float* ln2_g  = (const float*)d_in[12];
  const float* ln2_b  = (const float*)d_in[13];
  const float* w1     = (const float*)d_in[14];
  const float* b1     = (const float*)d_in[15];
  const float* w2     = (const float*)d_in[16];
  const float* b2     = (const float*)d_in[17];
  const float* fg     = (const float*)d_in[18];
  const float* fb     = (const float*)d_in[19];
  float* out = (float*)d_out;

  char* ws = (char*)d_ws;
  size_t off = 0;
  auto alloc = [&](size_t bytes)->char*{
    char* p = ws + off;
    off = (off + bytes + 255) & ~(size_t)255;
    return p;
  };
  u16*   WQKVT = (u16*)  alloc(3ull*3072*1024*2);
  u16*   WOT   = (u16*)  alloc(3ull*1024*1024*2);
  u16*   W1T   = (u16*)  alloc(3ull*4096*1024*2);
  u16*   W2T   = (u16*)  alloc(3ull*1024*4096*2);
  float* BQKV  = (float*)alloc(3ull*3072*4);
  float* COS   = (float*)alloc(4096ull*32*4);
  float* SIN   = (float*)alloc(4096ull*32*4);
  float* X     = (float*)alloc(4096ull*1024*4);
  u16*   HB    = (u16*)  alloc(4096ull*1024*2);
  u16*   QKV   = (u16*)  alloc(4096ull*3072*2);
  u16*   QR    = (u16*)  alloc(4096ull*1024*2);
  u16*   KR    = (u16*)  alloc(4096ull*1024*2);
  u16*   VR    = (u16*)  alloc(4096ull*1024*2);
  u16*   AO    = (u16*)  alloc(4096ull*1024*2);
  u16*   MB    = (u16*)  alloc(4096ull*4096*2);

  TJobs jb;
  int total = 0, ji = 0;
  for (int l=0;l<3;l++){
    const float* srcs[6] = { wq + (size_t)l*1024*1024, wk + (size_t)l*1024*1024, wv + (size_t)l*1024*1024,
                             wo + (size_t)l*1024*1024, w1 + (size_t)l*1024*4096, w2 + (size_t)l*4096*1024 };
    u16* dsts[6] = { WQKVT + (size_t)l*3072*1024, WQKVT + (size_t)l*3072*1024 + 1024*1024,
                     WQKVT + (size_t)l*3072*1024 + 2048*1024, WOT + (size_t)l*1024*1024,
                     W1T + (size_t)l*4096*1024, W2T + (size_t)l*1024*4096 };
    int Rs[6] = {1024,1024,1024,1024,1024,4096};
    int Cs[6] = {1024,1024,1024,1024,4096,1024};
    for (int k=0;k<6;k++){
      jb.src[ji] = srcs[k]; jb.dst[ji] = dsts[k]; jb.R[ji] = Rs[k]; jb.C[ji] = Cs[k];
      jb.start[ji] = total;
      total += (Rs[k]/32)*(Cs[k]/32);
      ji++;
    }
  }
  jb.start[18] = total;

  transpose_pack<<<total, 256, 0, stream>>>(jb);
  pack_bias<<<36, 256, 0, stream>>>(bq, bk, bv, BQKV);
  rope_table<<<512, 256, 0, stream>>>(pos, COS, SIN);

  for (int l=0;l<3;l++){
    const float* xin = (l == 0) ? hidden : X;
    ln_kernel<0><<<4096, 256, 0, stream>>>(xin, ln1_g + l*1024, ln1_b + l*1024, nullptr, HB);
    gemm_bt<0><<<dim3(24,32), 256, 0, stream>>>(HB, WQKVT + (size_t)l*3072*1024, BQKV + l*3072,
                                                nullptr, nullptr, QKV, 4096, 3072, 1024);
    rope_apply<<<8192, 256, 0, stream>>>(QKV, COS, SIN, QR, KR, VR);
    attn_kernel<<<512, 256, 0, stream>>>(QR, KR, VR, AO);
    gemm_bt<1><<<dim3(8,32), 256, 0, stream>>>(AO, WOT + (size_t)l*1024*1024, bo + l*1024,
                                               xin, X, nullptr, 4096, 1024, 1024);
    ln_kernel<0><<<4096, 256, 0, stream>>>(X, ln2_g + l*1024, ln2_b + l*1024, nullptr, HB);
    gemm_bt<2><<<dim3(32,32), 256, 0, stream>>>(HB, W1T + (size_t)l*4096*1024, b1 + l*4096,
                                                nullptr, nullptr, MB, 4096, 4096, 1024);
    gemm_bt<1><<<dim3(8,32), 256, 0, stream>>>(MB, W2T + (size_t)l*1024*4096, b2 + l*1024,
                                               X, X, nullptr, 4096, 1024, 4096);
  }
  ln_kernel<1><<<4096, 256, 0, stream>>>(X, fg, fb, out, nullptr);
}

// Round 2
// 1020.675 us; speedup vs baseline: 1.1383x; 1.1383x over previous
//
#include <hip/hip_runtime.h>

// ---------------- common types / helpers ----------------
typedef unsigned short u16;
typedef short s8v __attribute__((ext_vector_type(8)));
typedef float f4v __attribute__((ext_vector_type(4)));

__device__ __forceinline__ float bf2f(u16 u){ return __uint_as_float(((unsigned)u)<<16); }
__device__ __forceinline__ u16 f2bf(float f){
  unsigned u = __float_as_uint(f);
  unsigned r = u + 0x7fffu + ((u>>16)&1u);   // RNE
  return (u16)(r>>16);
}
__device__ __forceinline__ void gload16(const void* g, void* l){
  __builtin_amdgcn_global_load_lds((const __attribute__((address_space(1))) void*)g,
                                   (__attribute__((address_space(3))) void*)l, 16, 0, 0);
}

// ---------------- batched transpose + f32->bf16 convert ----------------
struct TJobs {
  const float* src[18];
  u16* dst[18];
  int R[18];
  int C[18];
  int start[19];
};

__global__ __launch_bounds__(256) void transpose_pack(TJobs jb){
  __shared__ float tile[32][33];
  int bid = blockIdx.x;
  int j = 0;
  while (bid >= jb.start[j+1]) j++;
  int t = bid - jb.start[j];
  int C = jb.C[j], R = jb.R[j];
  int ctiles = C >> 5;
  int ty = t / ctiles, tx = t - ty*ctiles;
  const float* src = jb.src[j];
  u16* dst = jb.dst[j];
  int tid = threadIdx.x;
  #pragma unroll
  for (int i=0;i<4;i++){
    int e = tid*4 + i;
    int lr = e >> 5, lc = e & 31;
    tile[lr][lc] = src[(long)(ty*32+lr)*C + tx*32+lc];
  }
  __syncthreads();
  #pragma unroll
  for (int i=0;i<4;i++){
    int e = tid*4 + i;
    int lc = e >> 5, lr = e & 31;
    dst[(long)(tx*32+lc)*R + ty*32+lr] = f2bf(tile[lr][lc]);
  }
}

__global__ __launch_bounds__(256) void pack_bias(const float* __restrict__ bq, const float* __restrict__ bk,
                                                 const float* __restrict__ bv, float* __restrict__ outp){
  int t = blockIdx.x*256 + threadIdx.x;
  if (t >= 3*3072) return;
  int l = t / 3072, c = t - l*3072;
  float v = (c < 1024) ? bq[l*1024+c] : (c < 2048) ? bk[l*1024+c-1024] : bv[l*1024+c-2048];
  outp[t] = v;
}

// ---------------- RoPE table + apply ----------------
__global__ __launch_bounds__(256) void rope_table(const int* __restrict__ pos, float* __restrict__ cosT,
                                                  float* __restrict__ sinT){
  int t = blockIdx.x*256 + threadIdx.x;     // 4096*32
  int j = t & 31, s = t >> 5;
  float f = expf(-(float)j * 0.28782313662425572f);   // ln(10000)/32
  float ang = (float)pos[s] * f;
  cosT[t] = cosf(ang);
  sinT[t] = sinf(ang);
}

__global__ __launch_bounds__(256) void rope_apply(const u16* __restrict__ qkv, const float* __restrict__ cosT,
                                                  const float* __restrict__ sinT, u16* __restrict__ qr,
                                                  u16* __restrict__ kr, u16* __restrict__ vr){
  int t = blockIdx.x*256 + threadIdx.x;     // 4096*16*32
  int j = t & 31, h = (t>>5) & 15, s = t >> 9;
  float c = cosT[(s<<5)+j], sn = sinT[(s<<5)+j];
  long base = (long)s*3072 + h*64 + j;
  long ob   = (long)s*1024 + h*64 + j;
  float q0 = bf2f(qkv[base]),      q1 = bf2f(qkv[base+32]);
  float k0 = bf2f(qkv[base+1024]), k1 = bf2f(qkv[base+1056]);
  qr[ob] = f2bf(q0*c - q1*sn);  qr[ob+32] = f2bf(q1*c + q0*sn);
  kr[ob] = f2bf(k0*c - k1*sn);  kr[ob+32] = f2bf(k1*c + k0*sn);
  vr[ob] = qkv[base+2048];      vr[ob+32] = qkv[base+2080];
}

// ---------------- LayerNorm ----------------
__device__ __forceinline__ float block_sum(float v, float* red, int tid){
  #pragma unroll
  for (int m=1;m<64;m<<=1) v += __shfl_xor(v, m);
  int w = tid >> 6;
  if ((tid & 63) == 0) red[w] = v;
  __syncthreads();
  float r = red[0]+red[1]+red[2]+red[3];
  __syncthreads();
  return r;
}

template<int OUTF32>
__global__ __launch_bounds__(256) void ln_kernel(const float* __restrict__ x, const float* __restrict__ g,
                                                 const float* __restrict__ b, float* __restrict__ outF,
                                                 u16* __restrict__ outH){
  __shared__ float red[4];
  long row = blockIdx.x;
  int tid = threadIdx.x;
  const float4 xv = *reinterpret_cast<const float4*>(x + row*1024 + tid*4);
  float s = xv.x + xv.y + xv.z + xv.w;
  float mean = block_sum(s, red, tid) * (1.0f/1024.0f);
  float d0 = xv.x-mean, d1 = xv.y-mean, d2 = xv.z-mean, d3 = xv.w-mean;
  float ss = d0*d0 + d1*d1 + d2*d2 + d3*d3;
  float var = block_sum(ss, red, tid) * (1.0f/1024.0f);
  float rstd = rsqrtf(var + 1e-5f);
  int c = tid*4;
  const float4 gv = *reinterpret_cast<const float4*>(g + c);
  const float4 bv = *reinterpret_cast<const float4*>(b + c);
  float y0 = d0*rstd*gv.x + bv.x, y1 = d1*rstd*gv.y + bv.y;
  float y2 = d2*rstd*gv.z + bv.z, y3 = d3*rstd*gv.w + bv.w;
  if (OUTF32){
    float4 o; o.x=y0; o.y=y1; o.z=y2; o.w=y3;
    *reinterpret_cast<float4*>(outF + row*1024 + c) = o;
  } else {
    outH[row*1024 + c+0] = f2bf(y0);
    outH[row*1024 + c+1] = f2bf(y1);
    outH[row*1024 + c+2] = f2bf(y2);
    outH[row*1024 + c+3] = f2bf(y3);
  }
}

// ---------------- GEMM: C = A[M,K] * BT[N,K]^T (+bias, epilogue) ----------------
// 2-phase double-buffered pipeline: issue next tile's global_load_lds BEFORE
// current tile's ds_read+MFMA; single __syncthreads (vmcnt0+lgkmcnt0+barrier)
// per K-step AFTER compute, so load latency hides under the MFMA phase.
// EPI 0: outH = bf16(acc+bias)
// EPI 1: outF = resid + acc + bias   (f32)
// EPI 2: outH = bf16(gelu(acc+bias)) (exact gelu)
template<int EPI>
__global__ __launch_bounds__(256) void gemm_bt(const u16* __restrict__ A, const u16* __restrict__ BT,
                                               const float* __restrict__ bias, const float* __restrict__ resid,
                                               float* __restrict__ outF, u16* __restrict__ outH,
                                               int M, int N, int K){
  __shared__ u16 As[2][4096];   // [128][32] per buffer
  __shared__ u16 Bs[2][4096];   // [128][32] (rows = output cols)
  const int tid = threadIdx.x;
  // bijective XCD-aware swizzle (grids launched with nwg % 8 == 0)
  const int gx = N >> 7;
  const int nwg = gridDim.x;
  const int cpx = nwg >> 3;
  const int sbid = (blockIdx.x & 7) * cpx + (blockIdx.x >> 3);
  const int bn = sbid % gx, bm = sbid / gx;

  const int w = tid >> 6, lane = tid & 63;
  const int wr = w >> 1, wc = w & 1;
  const int l15 = lane & 15, k8 = (lane >> 4) * 8;

  f4v acc[4][4];
  #pragma unroll
  for (int i=0;i<4;i++)
    #pragma unroll
    for (int j=0;j<4;j++)
      acc[i][j] = (f4v){0.f,0.f,0.f,0.f};

  const int fe = tid * 8;                 // element offset of this thread's 16B chunk
  const int r0 = fe >> 5, c0 = fe & 31;   // rows 0..63
  const u16* ga0 = A  + ((long)(bm*128 + r0))*K + c0;
  const u16* gb0 = BT + ((long)(bn*128 + r0))*K + c0;
  const u16* ga1 = ga0 + (long)64*K;      // rows 64..127
  const u16* gb1 = gb0 + (long)64*K;

  const int nt = K >> 5;
  // prologue: stage tile 0 into buffer 0
  gload16(ga0, &As[0][fe]);
  gload16(ga1, &As[0][fe + 2048]);
  gload16(gb0, &Bs[0][fe]);
  gload16(gb1, &Bs[0][fe + 2048]);
  __syncthreads();

  int cur = 0;
  for (int t = 0; t < nt; ++t){
    // prefetch next tile into the other buffer (no wait here)
    if (t + 1 < nt){
      const int kn = (t + 1) << 5;
      gload16(ga0 + kn, &As[cur^1][fe]);
      gload16(ga1 + kn, &As[cur^1][fe + 2048]);
      gload16(gb0 + kn, &Bs[cur^1][fe]);
      gload16(gb1 + kn, &Bs[cur^1][fe + 2048]);
    }
    // compute on current buffer
    s8v af[4], bfr[4];
    #pragma unroll
    for (int i=0;i<4;i++){
      af[i]  = *(const s8v*)&As[cur][(wr*64 + i*16 + l15)*32 + k8];
      bfr[i] = *(const s8v*)&Bs[cur][(wc*64 + i*16 + l15)*32 + k8];
    }
    #pragma unroll
    for (int mi=0;mi<4;mi++)
      #pragma unroll
      for (int nf=0;nf<4;nf++)
        acc[mi][nf] = __builtin_amdgcn_mfma_f32_16x16x32_bf16(af[mi], bfr[nf], acc[mi][nf], 0, 0, 0);
    __syncthreads();    // drains prefetch vmcnt + guards buffer reuse
    cur ^= 1;
  }

  const int r4 = (lane >> 4) * 4;
  #pragma unroll
  for (int mi=0;mi<4;mi++){
    int row = bm*128 + wr*64 + mi*16 + r4;
    #pragma unroll
    for (int nf=0;nf<4;nf++){
      int col = bn*128 + wc*64 + nf*16 + l15;
      float bcol = bias[col];
      #pragma unroll
      for (int r=0;r<4;r++){
        float v = acc[mi][nf][r] + bcol;
        long idx = (long)(row + r)*N + col;
        if (EPI == 0){
          outH[idx] = f2bf(v);
        } else if (EPI == 1){
          outF[idx] = resid[idx] + v;
        } else {
          float gl = 0.5f*v*(1.0f + erff(v*0.70710678118654752f));
          outH[idx] = f2bf(gl);
        }
      }
    }
  }
}

// ---------------- sliding-window attention (flash per 32-query wave tile) ----------------
// qr/kr/vr: [4096][16*64] bf16 ; ao: [4096][1024] bf16
__global__ __launch_bounds__(256) void attn_kernel(const u16* __restrict__ qr, const u16* __restrict__ kr,
                                                   const u16* __restrict__ vr, u16* __restrict__ ao){
  __shared__ u16 Pl[4][1280];   // per-wave [32][40]
  __shared__ u16 Vl[4][2304];   // per-wave [32][72]
  const int tid = threadIdx.x, w = tid >> 6, lane = tid & 63;
  const int task = blockIdx.x*4 + w;        // 2048 tasks
  const int head = task >> 7;
  const int q0 = (task & 127) * 32;
  const int l15 = lane & 15, lg = lane >> 4, k8 = lg * 8;

  s8v aq[2][2];
  #pragma unroll
  for (int mi=0;mi<2;mi++)
    #pragma unroll
    for (int kf=0;kf<2;kf++)
      aq[mi][kf] = *(const s8v*)&qr[(long)(q0 + mi*16 + l15)*1024 + head*64 + kf*32 + k8];

  f4v o[2][4];
  #pragma unroll
  for (int i=0;i<2;i++)
    #pragma unroll
    for (int j=0;j<4;j++)
      o[i][j] = (f4v){0.f,0.f,0.f,0.f};
  float mrun[2][4], lrun[2][4];
  #pragma unroll
  for (int i=0;i<2;i++)
    #pragma unroll
    for (int r=0;r<4;r++){ mrun[i][r] = -1e30f; lrun[i][r] = 0.f; }

  const int ktlo = (q0 >= 512) ? ((q0 - 511) >> 5) : 0;
  const int kthi = (q0 + 31) >> 5;

  for (int kt = ktlo; kt <= kthi; ++kt){
    const int k0 = kt * 32;
    // stage V tile [32][64] -> Vl[32][72]
    #pragma unroll
    for (int t=0;t<4;t++){
      int e = t*64 + lane;
      int r = e >> 3, c8 = (e & 7) * 8;
      *(s8v*)&Vl[w][r*72 + c8] = *(const s8v*)&vr[(long)(k0 + r)*1024 + head*64 + c8];
    }
    // QK^T
    s8v bk[2][2];
    #pragma unroll
    for (int nf=0;nf<2;nf++)
      #pragma unroll
      for (int kf=0;kf<2;kf++)
        bk[nf][kf] = *(const s8v*)&kr[(long)(k0 + nf*16 + l15)*1024 + head*64 + kf*32 + k8];
    f4v s[2][2];
    #pragma unroll
    for (int mi=0;mi<2;mi++)
      #pragma unroll
      for (int nf=0;nf<2;nf++){
        f4v z = (f4v){0.f,0.f,0.f,0.f};
        z = __builtin_amdgcn_mfma_f32_16x16x32_bf16(aq[mi][0], bk[nf][0], z, 0,0,0);
        z = __builtin_amdgcn_mfma_f32_16x16x32_bf16(aq[mi][1], bk[nf][1], z, 0,0,0);
        s[mi][nf] = z;
      }
    // online softmax (rows live in (lg, r); cols in l15 x nf)
    float alpha[2][4];
    #pragma unroll
    for (int mi=0;mi<2;mi++){
      #pragma unroll
      for (int r=0;r<4;r++){
        int q = q0 + mi*16 + lg*4 + r;
        int kk0 = k0 + l15, kk1 = k0 + 16 + l15;
        bool ok0 = (kk0 <= q) && (q - kk0 < 512);
        bool ok1 = (kk1 <= q) && (q - kk1 < 512);
        float sv0 = ok0 ? s[mi][0][r]*0.125f : -1e30f;
        float sv1 = ok1 ? s[mi][1][r]*0.125f : -1e30f;
        float tm = fmaxf(sv0, sv1);
        tm = fmaxf(tm, __shfl_xor(tm, 1));
        tm = fmaxf(tm, __shfl_xor(tm, 2));
        tm = fmaxf(tm, __shfl_xor(tm, 4));
        tm = fmaxf(tm, __shfl_xor(tm, 8));
        float mnew = fmaxf(mrun[mi][r], tm);
        float al = __expf(mrun[mi][r] - mnew);
        float p0 = ok0 ? __expf(sv0 - mnew) : 0.f;
        float p1 = ok1 ? __expf(sv1 - mnew) : 0.f;
        float rs = p0 + p1;
        rs += __shfl_xor(rs, 1);
        rs += __shfl_xor(rs, 2);
        rs += __shfl_xor(rs, 4);
        rs += __shfl_xor(rs, 8);
        mrun[mi][r] = mnew;
        lrun[mi][r] = lrun[mi][r]*al + rs;
        alpha[mi][r] = al;
        s[mi][0][r] = p0;
        s[mi][1][r] = p1;
      }
      #pragma unroll
      for (int df=0;df<4;df++)
        #pragma unroll
        for (int r=0;r<4;r++)
          o[mi][df][r] *= alpha[mi][r];
    }
    // P bounce: C-layout -> A-layout via LDS
    #pragma unroll
    for (int mi=0;mi<2;mi++)
      #pragma unroll
      for (int nf=0;nf<2;nf++)
        #pragma unroll
        for (int r=0;r<4;r++)
          Pl[w][(mi*16 + lg*4 + r)*40 + nf*16 + l15] = f2bf(s[mi][nf][r]);
    s8v ap[2];
    #pragma unroll
    for (int mi=0;mi<2;mi++)
      ap[mi] = *(const s8v*)&Pl[w][(mi*16 + l15)*40 + k8];
    s8v bv[4];
    #pragma unroll
    for (int df=0;df<4;df++){
      #pragma unroll
      for (int i=0;i<8;i++)
        bv[df][i] = (short)Vl[w][(k8 + i)*72 + df*16 + l15];
    }
    #pragma unroll
    for (int mi=0;mi<2;mi++)
      #pragma unroll
      for (int df=0;df<4;df++)
        o[mi][df] = __builtin_amdgcn_mfma_f32_16x16x32_bf16(ap[mi], bv[df], o[mi][df], 0,0,0);
  }
  // epilogue
  #pragma unroll
  for (int mi=0;mi<2;mi++)
    #pragma unroll
    for (int df=0;df<4;df++)
      #pragma unroll
      for (int r=0;r<4;r++){
        long row = q0 + mi*16 + lg*4 + r;
        int col = head*64 + df*16 + l15;
        ao[row*1024 + col] = f2bf(o[mi][df][r] / lrun[mi][r]);
      }
}

// ---------------- host ----------------
extern "C" void kernel_launch(void* const* d_in, const int* in_sizes, int n_in,
                              void* d_out, int out_size, void* d_ws, size_t ws_size,
                              hipStream_t stream){
  const float* hidden = (const float*)d_in[0];
  const int*   pos    = (const int*)d_in[1];
  const float* ln1_g  = (const float*)d_in[2];
  const float* ln1_b  = (const float*)d_in[3];
  const float* wq     = (const float*)d_in[4];
  const float* bq     = (const float*)d_in[5];
  const float* wk     = (const float*)d_in[6];
  const float* bk     = (const float*)d_in[7];
  const float* wv     = (const float*)d_in[8];
  const float* bv     = (const float*)d_in[9];
  const float* wo     = (const float*)d_in[10];
  const float* bo     = (const float*)d_in[11];
  const float* ln2_g  = (const float*)d_in[12];
  const float* ln2_b  = (const float*)d_in[13];
  const float* w1     = (const float*)d_in[14];
  const float* b1     = (const float*)d_in[15];
  const float* w2     = (const float*)d_in[16];
  const float* b2     = (const float*)d_in[17];
  const float* fg     = (const float*)d_in[18];
  const float* fb     = (const float*)d_in[19];
  float* out = (float*)d_out;

  char* ws = (char*)d_ws;
  size_t off = 0;
  auto alloc = [&](size_t bytes)->char*{
    char* p = ws + off;
    off = (off + bytes + 255) & ~(size_t)255;
    return p;
  };
  u16*   WQKVT = (u16*)  alloc(3ull*3072*1024*2);
  u16*   WOT   = (u16*)  alloc(3ull*1024*1024*2);
  u16*   W1T   = (u16*)  alloc(3ull*4096*1024*2);
  u16*   W2T   = (u16*)  alloc(3ull*1024*4096*2);
  float* BQKV  = (float*)alloc(3ull*3072*4);
  float* COS   = (float*)alloc(4096ull*32*4);
  float* SIN   = (float*)alloc(4096ull*32*4);
  float* X     = (float*)alloc(4096ull*1024*4);
  u16*   HB    = (u16*)  alloc(4096ull*1024*2);
  u16*   QKV   = (u16*)  alloc(4096ull*3072*2);
  u16*   QR    = (u16*)  alloc(4096ull*1024*2);
  u16*   KR    = (u16*)  alloc(4096ull*1024*2);
  u16*   VR    = (u16*)  alloc(4096ull*1024*2);
  u16*   AO    = (u16*)  alloc(4096ull*1024*2);
  u16*   MB    = (u16*)  alloc(4096ull*4096*2);

  TJobs jb;
  int total = 0, ji = 0;
  for (int l=0;l<3;l++){
    const float* srcs[6] = { wq + (size_t)l*1024*1024, wk + (size_t)l*1024*1024, wv + (size_t)l*1024*1024,
                             wo + (size_t)l*1024*1024, w1 + (size_t)l*1024*4096, w2 + (size_t)l*4096*1024 };
    u16* dsts[6] = { WQKVT + (size_t)l*3072*1024, WQKVT + (size_t)l*3072*1024 + 1024*1024,
                     WQKVT + (size_t)l*3072*1024 + 2048*1024, WOT + (size_t)l*1024*1024,
                     W1T + (size_t)l*4096*1024, W2T + (size_t)l*1024*4096 };
    int Rs[6] = {1024,1024,1024,1024,1024,4096};
    int Cs[6] = {1024,1024,1024,1024,4096,1024};
    for (int k=0;k<6;k++){
      jb.src[ji] = srcs[k]; jb.dst[ji] = dsts[k]; jb.R[ji] = Rs[k]; jb.C[ji] = Cs[k];
      jb.start[ji] = total;
      total += (Rs[k]/32)*(Cs[k]/32);
      ji++;
    }
  }
  jb.start[18] = total;

  transpose_pack<<<total, 256, 0, stream>>>(jb);
  pack_bias<<<36, 256, 0, stream>>>(bq, bk, bv, BQKV);
  rope_table<<<512, 256, 0, stream>>>(pos, COS, SIN);

  for (int l=0;l<3;l++){
    const float* xin = (l == 0) ? hidden : X;
    ln_kernel<0><<<4096, 256, 0, stream>>>(xin, ln1_g + l*1024, ln1_b + l*1024, nullptr, HB);
    gemm_bt<0><<<24*32, 256, 0, stream>>>(HB, WQKVT + (size_t)l*3072*1024, BQKV + l*3072,
                                          nullptr, nullptr, QKV, 4096, 3072, 1024);
    rope_apply<<<8192, 256, 0, stream>>>(QKV, COS, SIN, QR, KR, VR);
    attn_kernel<<<512, 256, 0, stream>>>(QR, KR, VR, AO);
    gemm_bt<1><<<8*32, 256, 0, stream>>>(AO, WOT + (size_t)l*1024*1024, bo + l*1024,
                                         xin, X, nullptr, 4096, 1024, 1024);
    ln_kernel<0><<<4096, 256, 0, stream>>>(X, ln2_g + l*1024, ln2_b + l*1024, nullptr, HB);
    gemm_bt<2><<<32*32, 256, 0, stream>>>(HB, W1T + (size_t)l*4096*1024, b1 + l*4096,
                                          nullptr, nullptr, MB, 4096, 4096, 1024);
    gemm_bt<1><<<8*32, 256, 0, stream>>>(MB, W2T + (size_t)l*1024*4096, b2 + l*1024,
                                         X, X, nullptr, 4096, 1024, 4096);
  }
  ln_kernel<1><<<4096, 256, 0, stream>>>(X, fg, fb, out, nullptr);
}